// Round 12
// baseline (218.339 us; speedup 1.0000x reference)
//
#include <hip/hip_runtime.h>

// ---------------------------------------------------------------------------
// RGAT 2-hop, N=100000, E=1600000, D=64, R=64.
// R25 = R22 with integer-only build speedup (R24 post-mortem: ANY change to
// hop fp-chain compilation context -- restructure, outlining, fusion --
// lands in the 2.3-3.3e-2 failure band (R17/R18/R24). HOP IS FROZEN as its
// own byte-identical kernel. Coop launch banned (R23). Gaps structural.)
// - buildA: NBA 256->512 (35KB LDS -> 4 blocks/CU vs 2; half the LDS
//   critical path per block), SCAP 36->24 (lambda=4, overflow P~7e-6).
// - binB: gather switches to 8-lane groups over 512 segments (integer-side
//   loop only; Wuv/cast/deg/perm/csr-writeout branches byte-identical).
// - emb1b aliases the stream buffer (dead after binB) -> ws ~78MB <= R22.
// ---------------------------------------------------------------------------

#define NEG_SLOPE 0.2f
#define CAP 64
#define BKT_SHIFT 7                  // 128 nodes per bucket
#define SCAP 24                      // stream slots per (block,bucket) cell
#define NBA 512                      // buildA blocks
#define EPB_MAX 3136                 // max edges per buildA block (~3128)

__device__ __forceinline__ float b2f_lo(unsigned x) {
    return __uint_as_float(x << 16);
}
__device__ __forceinline__ float b2f_hi(unsigned x) {
    return __uint_as_float(x & 0xffff0000u);
}
__device__ __forceinline__ unsigned short f2b(float x) {  // RNE
    unsigned u = __float_as_uint(x);
    unsigned r = u + 0x7fffu + ((u >> 16) & 1u);
    return (unsigned short)(r >> 16);
}

// D = a.bf16[0]*b.bf16[0] + a.bf16[1]*b.bf16[1] + c   (one VOP3P instr)
__device__ __forceinline__ float dot2bf(unsigned a, unsigned b, float c) {
    float d;
    asm("v_dot2_f32_bf16 %0, %1, %2, %3" : "=v"(d) : "v"(a), "v"(b), "v"(c));
    return d;
}

// sum over the 16 lanes of a row-group; result in ALL 16 lanes. VALU pipe.
__device__ __forceinline__ float ror_sum16(float x) {
#define ROR_ADD(ctrl)                                                          \
    x += __int_as_float(                                                       \
        __builtin_amdgcn_update_dpp(0, __float_as_int(x), ctrl, 0xf, 0xf, true))
    ROR_ADD(0x121);  // row_ror:1
    ROR_ADD(0x122);  // row_ror:2
    ROR_ADD(0x124);  // row_ror:4
    ROR_ADD(0x128);  // row_ror:8
#undef ROR_ADD
    return x;
}

// ---------------- build phase A: block-local counting sort --------------
// 512 blocks x 512 threads, ~3128 edges each. Sort by bucket in LDS, then
// sequential write-out into fixed per-(block,bucket) stream cells.
__global__ __launch_bounds__(512) void buildA_kernel(
    const int* __restrict__ head, const int* __restrict__ tail,
    const int* __restrict__ etype, unsigned* __restrict__ stream,
    unsigned char* __restrict__ cnts, int E4, int nbkt) {
    __shared__ int hist[1024];            // counts -> scan -> cursors
    __shared__ int excl[1024];            // exclusive prefix snapshot
    __shared__ int tsum[512];
    __shared__ uint2 sortedLDS[EPB_MAX];  // (entry, dst)  ~25 KB
    int bid = blockIdx.x;
    int t = threadIdx.x;
    int i0 = (int)((long)bid * E4 / NBA);
    int i1 = (int)((long)(bid + 1) * E4 / NBA);
    int n = (i1 - i0) * 4;
    for (int i = t; i < 1024; i += 512) hist[i] = 0;
    __syncthreads();
    // pass 1: histogram (int4 loads)
    for (int i = i0 + t; i < i1; i += 512) {
        int4 h = *(const int4*)(head + (long)i * 4);
        atomicAdd(&hist[h.x >> BKT_SHIFT], 1);
        atomicAdd(&hist[h.y >> BKT_SHIFT], 1);
        atomicAdd(&hist[h.z >> BKT_SHIFT], 1);
        atomicAdd(&hist[h.w >> BKT_SHIFT], 1);
    }
    __syncthreads();
    // 2-level exclusive scan over 1024 bins (2 bins/thread)
    int c0 = hist[2 * t], c1 = hist[2 * t + 1];
    int s = c0 + c1;
    tsum[t] = s;
    __syncthreads();
    for (int off = 1; off < 512; off <<= 1) {
        int v = (t >= off) ? tsum[t - off] : 0;
        __syncthreads();
        tsum[t] += v;
        __syncthreads();
    }
    int run = tsum[t] - s;  // exclusive prefix for bin 2t
    hist[2 * t] = run;       excl[2 * t] = run;
    hist[2 * t + 1] = run + c0; excl[2 * t + 1] = run + c0;
    __syncthreads();
    // pass 2: scatter (entry, dst) into LDS at sorted position
    for (int i = i0 + t; i < i1; i += 512) {
        int4 h = *(const int4*)(head + (long)i * 4);
        int4 tl = *(const int4*)(tail + (long)i * 4);
        int4 q = *(const int4*)(etype + (long)i * 4);
#pragma unroll
        for (int u = 0; u < 4; ++u) {
            int hh = (u == 0) ? h.x : (u == 1) ? h.y : (u == 2) ? h.z : h.w;
            int tt = (u == 0) ? tl.x : (u == 1) ? tl.y : (u == 2) ? tl.z : tl.w;
            int qq = (u == 0) ? q.x : (u == 1) ? q.y : (u == 2) ? q.z : q.w;
            int b = hh >> BKT_SHIFT;
            int pos = atomicAdd(&hist[b], 1);
            int local = pos - excl[b];
            unsigned entry = ((unsigned)(hh & 127) << 23) |
                             ((unsigned)tt << 6) | (unsigned)qq;
            unsigned dst = (local < SCAP)
                ? (unsigned)(((long)bid * nbkt + b) * SCAP + local)
                : 0xFFFFFFFFu;
            sortedLDS[pos] = make_uint2(entry, dst);
        }
    }
    __syncthreads();
    // sequential write-out: consecutive i -> consecutive dst within runs
    for (int i = t; i < n; i += 512) {
        uint2 v = sortedLDS[i];
        if (v.y != 0xFFFFFFFFu) stream[v.y] = v.x;
    }
    // per-cell counts for binB
    for (int b = t; b < nbkt; b += 512)
        cnts[bid * nbkt + b] = (unsigned char)min(hist[b] - excl[b], SCAP);
}

// ---------------- Phase B (+ Wuv + cast roles) --------------------------
// blocks [0,nbkt): per-bucket LDS CSR build (8-lane-group segment reads);
// [nbkt, nbkt+wuvB): Wuv projection (2 relations/block, math == R22);
// rest: ent -> bf16 cast (1024 float4/block, math == R22).
__global__ __launch_bounds__(256) void binB_kernel(
    const unsigned char* __restrict__ cnts, const unsigned* __restrict__ stream,
    int* __restrict__ deg, int* __restrict__ csr, int* __restrict__ perm,
    const float* __restrict__ W, const float* __restrict__ rel,
    unsigned short* __restrict__ Wuvb, const float* __restrict__ ent,
    unsigned short* __restrict__ entb, int nbkt, int N, int n4, int R,
    int wuvB) {
    __shared__ int cnt[128];
    __shared__ int hist[CAP + 2];
    __shared__ unsigned csrS[128 * 65];  // 33.3 KB, skewed stride
    int bid = blockIdx.x;
    int t = threadIdx.x;
    if (bid >= nbkt + wuvB) {
        // ---- cast role ----
        int i = (bid - nbkt - wuvB) * 1024 + t;
#pragma unroll
        for (int j = 0; j < 4; ++j, i += 256) {
            if (i < n4) {
                float4 v = *(const float4*)(ent + (long)i * 4);
                ushort4 o = {f2b(v.x), f2b(v.y), f2b(v.z), f2b(v.w)};
                *(ushort4*)(entb + (long)i * 4) = o;
            }
        }
        return;
    }
    if (bid >= nbkt) {
        // ---- Wuv role: 2 relations/block, 128 threads each ----
        int r = (bid - nbkt) * 2 + (t >> 7);
        int i = t & 127;
        if (r < R) {
            float s = 0.f;
#pragma unroll
            for (int j = 0; j < 64; ++j) s += W[i * 64 + j] * rel[r * 64 + j];
            int d = i & 63, half = i >> 6;
            Wuvb[r * 128 + (d >> 2) * 8 + half * 4 + (d & 3)] = f2b(s);
        }
        return;
    }
    // ---- binB role ----
    int b = bid;
    if (t < 128) cnt[t] = 0;
    if (t < CAP + 2) hist[t] = 0;
    __syncthreads();
    // gather: 8-lane groups walk the 512 segments (short cells, lambda=4)
    {
        int lane = t & 7;
        for (int seg = t >> 3; seg < NBA; seg += 32) {
            int c = cnts[seg * nbkt + b];
            const unsigned* sp = stream + ((long)seg * nbkt + b) * SCAP;
            for (int k = lane; k < c; k += 8) {
                unsigned e = sp[k];
                int l = (int)(e >> 23) & 127;
                int p = atomicAdd(&cnt[l], 1);
                if (p < CAP) csrS[l * 65 + p] = e & 0x7FFFFFu;
            }
        }
    }
    __syncthreads();
    // deg write + degree-histogram rank
    int l = t, d = 0, rank = 0;
    bool v = false;
    if (l < 128) {
        int node = (b << BKT_SHIFT) + l;
        v = node < N;
        if (v) {
            deg[node] = cnt[l];
            d = min(cnt[l], CAP);
            rank = atomicAdd(&hist[d], 1);
        }
    }
    __syncthreads();
    if (t == 0) {  // exclusive prefix over 65 bins
        int s = 0;
        for (int i = 0; i <= CAP; ++i) { int tt = hist[i]; hist[i] = s; s += tt; }
    }
    __syncthreads();
    if (v) perm[(b << BKT_SHIFT) + hist[d] + rank] = (b << BKT_SHIFT) + l;
    // coalesced csr write-out: 16 groups of 16 lanes; groups within a wave
    // take nodes spaced 8 apart -> LDS bank windows overlap 2-way (free).
    int w4 = t >> 6, lane = t & 63;
    int q = lane >> 4, sL = lane & 15;
    for (int j = 0; j < 8; ++j) {
        int ln = ((j & 3) << 5) + (q << 3) + ((j >> 2) << 2) + w4;  // 0..127
        int node = (b << BKT_SHIFT) + ln;
        if (node < N) {
            int dcl = min(cnt[ln], CAP);
            for (int r = 0; r * 16 < dcl; ++r)
                csr[(long)node * CAP + r * 16 + sL] =
                    (int)csrS[ln * 65 + r * 16 + sL];
        }
    }
}

// ---------------- fused hop (16-lane groups) ----------------
// 512 threads = 8 waves = 32 nodes per block. Group = 16 lanes = 1 node,
// lane s owns dims 4s..4s+3. Nodes taken via degree-sorted perm.
// BYTE-IDENTICAL to R19/R21/R22's hop (FROZEN: R17/R18/R24 all failed via
// fp-codegen drift from restructure/outlining/fusion).
__global__ __launch_bounds__(512) void hop_kernel(
    const int* __restrict__ degp, const int* __restrict__ csr,
    const int* __restrict__ perm,
    const unsigned short* __restrict__ Wuvb,
    const unsigned short* __restrict__ embb, const float* res_prev,
    unsigned short* embb_out, float* res_out, int N) {
    __shared__ unsigned short sUV[64 * 136];  // 17 KB, skewed stride
    for (int k = threadIdx.x; k < 64 * 128; k += 512) {
        int r = k >> 7, q = k & 127;
        sUV[r * 136 + q] = Wuvb[k];
    }
    __syncthreads();

    int tid = threadIdx.x;
    int s = tid & 15;
    int gi = blockIdx.x * 32 + (tid >> 4);
    bool valid = gi < N;
    int node = valid ? perm[gi] : 0;
    long nb64 = (long)node * 64;

    uint2 hdp = valid ? *(const uint2*)(embb + nb64 + s * 4)
                      : make_uint2(0u, 0u);

    int deg = valid ? min(degp[node], CAP) : 0;
    int r0 = node * CAP;
    // wave-uniform min/max degree over the wave's 4 groups (near-equal now)
    int dmin = min(min(__shfl(deg, 0), __shfl(deg, 16)),
                   min(__shfl(deg, 32), __shfl(deg, 48)));
    int dmax = max(max(__shfl(deg, 0), __shfl(deg, 16)),
                   max(__shfl(deg, 32), __shfl(deg, 48)));

    float a0 = 0.f, a1 = 0.f, a2 = 0.f, a3 = 0.f, l = 0.f;

    auto edge_body = [&](int pe, uint2 rw, bool gated, int idx) {
        int rr = pe & 63;
        uint4 uv = *(const uint4*)(sUV + rr * 136 + s * 8);
        float sd = dot2bf(hdp.x, uv.x, 0.f);   // hd01 . U01
        sd = dot2bf(hdp.y, uv.y, sd);          // hd23 . U23
        sd = dot2bf(rw.x, uv.z, sd);           // row01 . V01
        sd = dot2bf(rw.y, uv.w, sd);           // row23 . V23
        sd = ror_sum16(sd);                    // 64-dot in all 16 lanes
        float p = fmaxf(sd, NEG_SLOPE * sd);   // leaky (slope<1)
        float w = __expf(p);
        if (gated) w = (idx < deg) ? w : 0.f;
        l += w;
        float e0 = b2f_lo(rw.x), e1 = b2f_hi(rw.x);
        float e2 = b2f_lo(rw.y), e3 = b2f_hi(rw.y);
        a0 += w * e0; a1 += w * e1; a2 += w * e2; a3 += w * e3;
    };

    int c = 0;
    // fast path: 8 edges/iter, all groups full, no gating
    for (; c + 8 <= dmin; c += 8) {
        uint4 ea = *(const uint4*)(csr + r0 + c);
        uint4 eb = *(const uint4*)(csr + r0 + c + 4);
        int pe[8] = {(int)ea.x, (int)ea.y, (int)ea.z, (int)ea.w,
                     (int)eb.x, (int)eb.y, (int)eb.z, (int)eb.w};
        uint2 rw[8];
#pragma unroll
        for (int u = 0; u < 8; ++u)
            rw[u] = *(const uint2*)(embb + (long)(pe[u] >> 6) * 64 + s * 4);
#pragma unroll
        for (int u = 0; u < 8; ++u) edge_body(pe[u], rw[u], false, 0);
    }
    // ungated 4-wide mid loop
    for (; c + 4 <= dmin; c += 4) {
        uint4 e4 = *(const uint4*)(csr + r0 + c);
        int pe[4] = {(int)e4.x, (int)e4.y, (int)e4.z, (int)e4.w};
        uint2 rw[4];
#pragma unroll
        for (int u = 0; u < 4; ++u)
            rw[u] = *(const uint2*)(embb + (long)(pe[u] >> 6) * 64 + s * 4);
#pragma unroll
        for (int u = 0; u < 4; ++u) edge_body(pe[u], rw[u], false, 0);
    }
    // gated tail: 4 edges/iter; pe forced 0 before gather (poison safety)
    for (; c < dmax; c += 4) {
        uint4 e4 = *(const uint4*)(csr + r0 + c);
        int pe[4];
        pe[0] = (c + 0 < deg) ? (int)e4.x : 0;
        pe[1] = (c + 1 < deg) ? (int)e4.y : 0;
        pe[2] = (c + 2 < deg) ? (int)e4.z : 0;
        pe[3] = (c + 3 < deg) ? (int)e4.w : 0;
        uint2 rw[4];
#pragma unroll
        for (int u = 0; u < 4; ++u)
            rw[u] = *(const uint2*)(embb + (long)(pe[u] >> 6) * 64 + s * 4);
#pragma unroll
        for (int u = 0; u < 4; ++u) edge_body(pe[u], rw[u], true, c + u);
    }

    if (valid) {
        float hd0 = b2f_lo(hdp.x), hd1 = b2f_hi(hdp.x);
        float hd2 = b2f_lo(hdp.y), hd3 = b2f_hi(hdp.y);
        float inv = (l > 0.f) ? 1.f / l : 0.f;
        float v0 = hd0 + a0 * inv, v1 = hd1 + a1 * inv;
        float v2 = hd2 + a2 * inv, v3 = hd3 + a3 * inv;
        float sq = v0 * v0 + v1 * v1 + v2 * v2 + v3 * v3;
        sq = ror_sum16(sq);                       // group-uniform
        float rn = 1.f / fmaxf(sqrtf(sq), 1e-12f);
        v0 *= rn; v1 *= rn; v2 *= rn; v3 *= rn;
        if (embb_out) {
            ushort4 o = {f2b(v0), f2b(v1), f2b(v2), f2b(v3)};
            *(ushort4*)(embb_out + nb64 + s * 4) = o;
        }
        float4 rp = *(const float4*)(res_prev + nb64 + s * 4);
        float4 ro = {0.5f * rp.x + v0, 0.5f * rp.y + v1,
                     0.5f * rp.z + v2, 0.5f * rp.w + v3};
        *(float4*)(res_out + nb64 + s * 4) = ro;
    }
}

extern "C" void kernel_launch(void* const* d_in, const int* in_sizes, int n_in,
                              void* d_out, int out_size, void* d_ws, size_t ws_size,
                              hipStream_t stream_) {
    const int*   edge_index = (const int*)d_in[0];   // [2, E]
    const int*   etype      = (const int*)d_in[1];   // [E]
    const float* ent        = (const float*)d_in[2]; // [N, 64]
    const float* rel        = (const float*)d_in[3]; // [R, 64]
    const float* W          = (const float*)d_in[4]; // [128, 64]

    const int E = in_sizes[1];
    const int N = in_sizes[2] / 64;
    const int R = in_sizes[3] / 64;
    const int* head = edge_index;
    const int* tail = edge_index + E;
    float* out = (float*)d_out;

    const int nbkt = ((N - 1) >> BKT_SHIFT) + 1;  // 782 for N=100000

    // workspace layout (~78 MB; emb1b aliases stream, dead after binB)
    char* w = (char*)d_ws;
    unsigned short* Wuvb = (unsigned short*)w;  w += (size_t)R * 128 * 2;
    int* deg = (int*)w;                         w += ((size_t)N + 64) * 4;
    int* csr = (int*)w;                         w += (size_t)N * CAP * 4;
    unsigned* bstream = (unsigned*)w;           w += (size_t)NBA * nbkt * SCAP * 4;
    unsigned char* cnts = (unsigned char*)w;    w += ((size_t)NBA * nbkt + 3) & ~3ull;
    unsigned short* entb = (unsigned short*)w;  w += (size_t)N * 64 * 2;
    int* perm = (int*)w;                        w += ((size_t)N + 64) * 4;
    unsigned short* emb1b = (unsigned short*)bstream;  // alias (see above)

    const int n4 = N * 16;                      // float4s to cast
    const int E4 = E / 4;                       // 400000 int4-edges
    const int wuvB = (R + 1) / 2;               // 32 Wuv blocks
    const int castB = (n4 + 1023) / 1024;       // 1563 cast blocks
    const int hb = (N + 31) / 32;

    // phase A: block-local counting sort into fixed stream cells
    buildA_kernel<<<NBA, 512, 0, stream_>>>(head, tail, etype, bstream,
                                            cnts, E4, nbkt);

    // phase B + Wuv + cast roles
    binB_kernel<<<nbkt + wuvB + castB, 256, 0, stream_>>>(
        cnts, bstream, deg, csr, perm, W, rel, Wuvb, ent, entb,
        nbkt, N, n4, R, wuvB);

    // hop 1
    hop_kernel<<<hb, 512, 0, stream_>>>(deg, csr, perm, Wuvb, entb, ent,
                                        emb1b, out, N);
    // hop 2 (res in place)
    hop_kernel<<<hb, 512, 0, stream_>>>(deg, csr, perm, Wuvb, emb1b, out,
                                        nullptr, out, N);
}

// Round 13
// 215.136 us; speedup vs baseline: 1.0149x; 1.0149x over previous
//
#include <hip/hip_runtime.h>

// ---------------------------------------------------------------------------
// RGAT 2-hop, N=100000, E=1600000, D=64, R=64.
// R26 = R25 with build-side overlap reclaimed (R25 post-mortem: NBA 512
// was neutral -> buildA is barrier/scan-bound; attack concurrency instead):
// - Wuv + cast roles moved INTO buildA's kernel (R21's exact 512-thread
//   role code, which passed at 1 ulp): their ~30MB streaming traffic
//   overlaps buildA's LDS-barrier-bound blocks instead of serializing
//   behind the buildA->binB gap.
// - binB: pure role, 512 threads (gather = 64 groups of 8 lanes over 512
//   segments; csr write-out 32 groups x 4 rows). Integer-side only.
// - hop kernels BYTE-IDENTICAL, same launch config (FROZEN: R17/R18/R24
//   all failed via fp-codegen drift from restructure/outlining/fusion).
// - Coop launch banned (R23). Gaps (3 x ~11us) structural.
// ---------------------------------------------------------------------------

#define NEG_SLOPE 0.2f
#define CAP 64
#define BKT_SHIFT 7                  // 128 nodes per bucket
#define SCAP 24                      // stream slots per (block,bucket) cell
#define NBA 512                      // buildA blocks
#define EPB_MAX 3136                 // max edges per buildA block (~3128)

__device__ __forceinline__ float b2f_lo(unsigned x) {
    return __uint_as_float(x << 16);
}
__device__ __forceinline__ float b2f_hi(unsigned x) {
    return __uint_as_float(x & 0xffff0000u);
}
__device__ __forceinline__ unsigned short f2b(float x) {  // RNE
    unsigned u = __float_as_uint(x);
    unsigned r = u + 0x7fffu + ((u >> 16) & 1u);
    return (unsigned short)(r >> 16);
}

// D = a.bf16[0]*b.bf16[0] + a.bf16[1]*b.bf16[1] + c   (one VOP3P instr)
__device__ __forceinline__ float dot2bf(unsigned a, unsigned b, float c) {
    float d;
    asm("v_dot2_f32_bf16 %0, %1, %2, %3" : "=v"(d) : "v"(a), "v"(b), "v"(c));
    return d;
}

// sum over the 16 lanes of a row-group; result in ALL 16 lanes. VALU pipe.
__device__ __forceinline__ float ror_sum16(float x) {
#define ROR_ADD(ctrl)                                                          \
    x += __int_as_float(                                                       \
        __builtin_amdgcn_update_dpp(0, __float_as_int(x), ctrl, 0xf, 0xf, true))
    ROR_ADD(0x121);  // row_ror:1
    ROR_ADD(0x122);  // row_ror:2
    ROR_ADD(0x124);  // row_ror:4
    ROR_ADD(0x128);  // row_ror:8
#undef ROR_ADD
    return x;
}

// ---------------- k1: buildA || Wuv || cast -----------------------------
// blocks [0,NBA): counting-sort into fixed per-(block,bucket) cells;
// [NBA,NBA+16): Wuv projection (R21 code); rest: ent->bf16 cast (R21 code).
__global__ __launch_bounds__(512) void buildA_kernel(
    const int* __restrict__ head, const int* __restrict__ tail,
    const int* __restrict__ etype, unsigned* __restrict__ stream,
    unsigned char* __restrict__ cnts, const float* __restrict__ W,
    const float* __restrict__ rel, unsigned short* __restrict__ Wuvb,
    const float* __restrict__ ent, unsigned short* __restrict__ entb,
    int E4, int nbkt, int n4, int R) {
    __shared__ int hist[1024];            // counts -> scan -> cursors
    __shared__ int excl[1024];            // exclusive prefix snapshot
    __shared__ int tsum[512];
    __shared__ uint2 sortedLDS[EPB_MAX];  // (entry, dst)  ~25 KB
    int bid = blockIdx.x;
    int t = threadIdx.x;
    if (bid >= NBA + 16) {
        // ---- cast role (R21 verbatim) ----
        int i = (bid - NBA - 16) * 512 + t;
        if (i < n4) {
            float4 v = *(const float4*)(ent + (long)i * 4);
            ushort4 o = {f2b(v.x), f2b(v.y), f2b(v.z), f2b(v.w)};
            *(ushort4*)(entb + (long)i * 4) = o;
        }
        return;
    }
    if (bid >= NBA) {
        // ---- Wuv role: 4 relations/block, 128 threads each (R21) ----
        int r = (bid - NBA) * 4 + (t >> 7);
        int i = t & 127;
        if (r < R) {
            float s = 0.f;
#pragma unroll
            for (int j = 0; j < 64; ++j) s += W[i * 64 + j] * rel[r * 64 + j];
            int d = i & 63, half = i >> 6;
            Wuvb[r * 128 + (d >> 2) * 8 + half * 4 + (d & 3)] = f2b(s);
        }
        return;
    }
    // ---- buildA role (R25 verbatim) ----
    int i0 = (int)((long)bid * E4 / NBA);
    int i1 = (int)((long)(bid + 1) * E4 / NBA);
    int n = (i1 - i0) * 4;
    for (int i = t; i < 1024; i += 512) hist[i] = 0;
    __syncthreads();
    // pass 1: histogram (int4 loads)
    for (int i = i0 + t; i < i1; i += 512) {
        int4 h = *(const int4*)(head + (long)i * 4);
        atomicAdd(&hist[h.x >> BKT_SHIFT], 1);
        atomicAdd(&hist[h.y >> BKT_SHIFT], 1);
        atomicAdd(&hist[h.z >> BKT_SHIFT], 1);
        atomicAdd(&hist[h.w >> BKT_SHIFT], 1);
    }
    __syncthreads();
    // 2-level exclusive scan over 1024 bins (2 bins/thread)
    int c0 = hist[2 * t], c1 = hist[2 * t + 1];
    int s = c0 + c1;
    tsum[t] = s;
    __syncthreads();
    for (int off = 1; off < 512; off <<= 1) {
        int v = (t >= off) ? tsum[t - off] : 0;
        __syncthreads();
        tsum[t] += v;
        __syncthreads();
    }
    int run = tsum[t] - s;  // exclusive prefix for bin 2t
    hist[2 * t] = run;       excl[2 * t] = run;
    hist[2 * t + 1] = run + c0; excl[2 * t + 1] = run + c0;
    __syncthreads();
    // pass 2: scatter (entry, dst) into LDS at sorted position
    for (int i = i0 + t; i < i1; i += 512) {
        int4 h = *(const int4*)(head + (long)i * 4);
        int4 tl = *(const int4*)(tail + (long)i * 4);
        int4 q = *(const int4*)(etype + (long)i * 4);
#pragma unroll
        for (int u = 0; u < 4; ++u) {
            int hh = (u == 0) ? h.x : (u == 1) ? h.y : (u == 2) ? h.z : h.w;
            int tt = (u == 0) ? tl.x : (u == 1) ? tl.y : (u == 2) ? tl.z : tl.w;
            int qq = (u == 0) ? q.x : (u == 1) ? q.y : (u == 2) ? q.z : q.w;
            int b = hh >> BKT_SHIFT;
            int pos = atomicAdd(&hist[b], 1);
            int local = pos - excl[b];
            unsigned entry = ((unsigned)(hh & 127) << 23) |
                             ((unsigned)tt << 6) | (unsigned)qq;
            unsigned dst = (local < SCAP)
                ? (unsigned)(((long)bid * nbkt + b) * SCAP + local)
                : 0xFFFFFFFFu;
            sortedLDS[pos] = make_uint2(entry, dst);
        }
    }
    __syncthreads();
    // sequential write-out: consecutive i -> consecutive dst within runs
    for (int i = t; i < n; i += 512) {
        uint2 v = sortedLDS[i];
        if (v.y != 0xFFFFFFFFu) stream[v.y] = v.x;
    }
    // per-cell counts for binB
    for (int b = t; b < nbkt; b += 512)
        cnts[bid * nbkt + b] = (unsigned char)min(hist[b] - excl[b], SCAP);
}

// ---------------- k2: pure binB, 512 threads ----------------------------
// One block per 128-node bucket; gathers 512 fixed cells (8-lane groups),
// builds CSR rows in LDS, writes full 64B lines; deg + degree-sorted perm.
__global__ __launch_bounds__(512) void binB_kernel(
    const unsigned char* __restrict__ cnts, const unsigned* __restrict__ stream,
    int* __restrict__ deg, int* __restrict__ csr, int* __restrict__ perm,
    int nbkt, int N) {
    __shared__ int cnt[128];
    __shared__ int hist[CAP + 2];
    __shared__ unsigned csrS[128 * 65];  // 33.3 KB, skewed stride
    int b = blockIdx.x;
    int t = threadIdx.x;
    if (t < 128) cnt[t] = 0;
    if (t < CAP + 2) hist[t] = 0;
    __syncthreads();
    // gather: 64 groups of 8 lanes walk the 512 segments
    {
        int lane = t & 7;
        for (int seg = t >> 3; seg < NBA; seg += 64) {
            int c = cnts[seg * nbkt + b];
            const unsigned* sp = stream + ((long)seg * nbkt + b) * SCAP;
            for (int k = lane; k < c; k += 8) {
                unsigned e = sp[k];
                int l = (int)(e >> 23) & 127;
                int p = atomicAdd(&cnt[l], 1);
                if (p < CAP) csrS[l * 65 + p] = e & 0x7FFFFFu;
            }
        }
    }
    __syncthreads();
    // deg write + degree-histogram rank
    int l = t, d = 0, rank = 0;
    bool v = false;
    if (l < 128) {
        int node = (b << BKT_SHIFT) + l;
        v = node < N;
        if (v) {
            deg[node] = cnt[l];
            d = min(cnt[l], CAP);
            rank = atomicAdd(&hist[d], 1);
        }
    }
    __syncthreads();
    if (t == 0) {  // exclusive prefix over 65 bins
        int s = 0;
        for (int i = 0; i <= CAP; ++i) { int tt = hist[i]; hist[i] = s; s += tt; }
    }
    __syncthreads();
    if (v) perm[(b << BKT_SHIFT) + hist[d] + rank] = (b << BKT_SHIFT) + l;
    // csr write-out: 32 groups of 16 lanes, 4 rows each (ln, ln+32, ...)
    {
        int gid = t >> 4, sL = t & 15;
        for (int j = 0; j < 4; ++j) {
            int ln = (j << 5) + gid;
            int node = (b << BKT_SHIFT) + ln;
            if (node < N) {
                int dcl = min(cnt[ln], CAP);
                for (int r = 0; r * 16 < dcl; ++r)
                    csr[(long)node * CAP + r * 16 + sL] =
                        (int)csrS[ln * 65 + r * 16 + sL];
            }
        }
    }
}

// ---------------- fused hop (16-lane groups) ----------------
// 512 threads = 8 waves = 32 nodes per block. Group = 16 lanes = 1 node,
// lane s owns dims 4s..4s+3. Nodes taken via degree-sorted perm.
// BYTE-IDENTICAL to R19/R21/R22/R25's hop (FROZEN).
__global__ __launch_bounds__(512) void hop_kernel(
    const int* __restrict__ degp, const int* __restrict__ csr,
    const int* __restrict__ perm,
    const unsigned short* __restrict__ Wuvb,
    const unsigned short* __restrict__ embb, const float* res_prev,
    unsigned short* embb_out, float* res_out, int N) {
    __shared__ unsigned short sUV[64 * 136];  // 17 KB, skewed stride
    for (int k = threadIdx.x; k < 64 * 128; k += 512) {
        int r = k >> 7, q = k & 127;
        sUV[r * 136 + q] = Wuvb[k];
    }
    __syncthreads();

    int tid = threadIdx.x;
    int s = tid & 15;
    int gi = blockIdx.x * 32 + (tid >> 4);
    bool valid = gi < N;
    int node = valid ? perm[gi] : 0;
    long nb64 = (long)node * 64;

    uint2 hdp = valid ? *(const uint2*)(embb + nb64 + s * 4)
                      : make_uint2(0u, 0u);

    int deg = valid ? min(degp[node], CAP) : 0;
    int r0 = node * CAP;
    // wave-uniform min/max degree over the wave's 4 groups (near-equal now)
    int dmin = min(min(__shfl(deg, 0), __shfl(deg, 16)),
                   min(__shfl(deg, 32), __shfl(deg, 48)));
    int dmax = max(max(__shfl(deg, 0), __shfl(deg, 16)),
                   max(__shfl(deg, 32), __shfl(deg, 48)));

    float a0 = 0.f, a1 = 0.f, a2 = 0.f, a3 = 0.f, l = 0.f;

    auto edge_body = [&](int pe, uint2 rw, bool gated, int idx) {
        int rr = pe & 63;
        uint4 uv = *(const uint4*)(sUV + rr * 136 + s * 8);
        float sd = dot2bf(hdp.x, uv.x, 0.f);   // hd01 . U01
        sd = dot2bf(hdp.y, uv.y, sd);          // hd23 . U23
        sd = dot2bf(rw.x, uv.z, sd);           // row01 . V01
        sd = dot2bf(rw.y, uv.w, sd);           // row23 . V23
        sd = ror_sum16(sd);                    // 64-dot in all 16 lanes
        float p = fmaxf(sd, NEG_SLOPE * sd);   // leaky (slope<1)
        float w = __expf(p);
        if (gated) w = (idx < deg) ? w : 0.f;
        l += w;
        float e0 = b2f_lo(rw.x), e1 = b2f_hi(rw.x);
        float e2 = b2f_lo(rw.y), e3 = b2f_hi(rw.y);
        a0 += w * e0; a1 += w * e1; a2 += w * e2; a3 += w * e3;
    };

    int c = 0;
    // fast path: 8 edges/iter, all groups full, no gating
    for (; c + 8 <= dmin; c += 8) {
        uint4 ea = *(const uint4*)(csr + r0 + c);
        uint4 eb = *(const uint4*)(csr + r0 + c + 4);
        int pe[8] = {(int)ea.x, (int)ea.y, (int)ea.z, (int)ea.w,
                     (int)eb.x, (int)eb.y, (int)eb.z, (int)eb.w};
        uint2 rw[8];
#pragma unroll
        for (int u = 0; u < 8; ++u)
            rw[u] = *(const uint2*)(embb + (long)(pe[u] >> 6) * 64 + s * 4);
#pragma unroll
        for (int u = 0; u < 8; ++u) edge_body(pe[u], rw[u], false, 0);
    }
    // ungated 4-wide mid loop
    for (; c + 4 <= dmin; c += 4) {
        uint4 e4 = *(const uint4*)(csr + r0 + c);
        int pe[4] = {(int)e4.x, (int)e4.y, (int)e4.z, (int)e4.w};
        uint2 rw[4];
#pragma unroll
        for (int u = 0; u < 4; ++u)
            rw[u] = *(const uint2*)(embb + (long)(pe[u] >> 6) * 64 + s * 4);
#pragma unroll
        for (int u = 0; u < 4; ++u) edge_body(pe[u], rw[u], false, 0);
    }
    // gated tail: 4 edges/iter; pe forced 0 before gather (poison safety)
    for (; c < dmax; c += 4) {
        uint4 e4 = *(const uint4*)(csr + r0 + c);
        int pe[4];
        pe[0] = (c + 0 < deg) ? (int)e4.x : 0;
        pe[1] = (c + 1 < deg) ? (int)e4.y : 0;
        pe[2] = (c + 2 < deg) ? (int)e4.z : 0;
        pe[3] = (c + 3 < deg) ? (int)e4.w : 0;
        uint2 rw[4];
#pragma unroll
        for (int u = 0; u < 4; ++u)
            rw[u] = *(const uint2*)(embb + (long)(pe[u] >> 6) * 64 + s * 4);
#pragma unroll
        for (int u = 0; u < 4; ++u) edge_body(pe[u], rw[u], true, c + u);
    }

    if (valid) {
        float hd0 = b2f_lo(hdp.x), hd1 = b2f_hi(hdp.x);
        float hd2 = b2f_lo(hdp.y), hd3 = b2f_hi(hdp.y);
        float inv = (l > 0.f) ? 1.f / l : 0.f;
        float v0 = hd0 + a0 * inv, v1 = hd1 + a1 * inv;
        float v2 = hd2 + a2 * inv, v3 = hd3 + a3 * inv;
        float sq = v0 * v0 + v1 * v1 + v2 * v2 + v3 * v3;
        sq = ror_sum16(sq);                       // group-uniform
        float rn = 1.f / fmaxf(sqrtf(sq), 1e-12f);
        v0 *= rn; v1 *= rn; v2 *= rn; v3 *= rn;
        if (embb_out) {
            ushort4 o = {f2b(v0), f2b(v1), f2b(v2), f2b(v3)};
            *(ushort4*)(embb_out + nb64 + s * 4) = o;
        }
        float4 rp = *(const float4*)(res_prev + nb64 + s * 4);
        float4 ro = {0.5f * rp.x + v0, 0.5f * rp.y + v1,
                     0.5f * rp.z + v2, 0.5f * rp.w + v3};
        *(float4*)(res_out + nb64 + s * 4) = ro;
    }
}

extern "C" void kernel_launch(void* const* d_in, const int* in_sizes, int n_in,
                              void* d_out, int out_size, void* d_ws, size_t ws_size,
                              hipStream_t stream_) {
    const int*   edge_index = (const int*)d_in[0];   // [2, E]
    const int*   etype      = (const int*)d_in[1];   // [E]
    const float* ent        = (const float*)d_in[2]; // [N, 64]
    const float* rel        = (const float*)d_in[3]; // [R, 64]
    const float* W          = (const float*)d_in[4]; // [128, 64]

    const int E = in_sizes[1];
    const int N = in_sizes[2] / 64;
    const int R = in_sizes[3] / 64;
    const int* head = edge_index;
    const int* tail = edge_index + E;
    float* out = (float*)d_out;

    const int nbkt = ((N - 1) >> BKT_SHIFT) + 1;  // 782 for N=100000

    // workspace layout (~78 MB; emb1b aliases stream, dead after binB)
    char* w = (char*)d_ws;
    unsigned short* Wuvb = (unsigned short*)w;  w += (size_t)R * 128 * 2;
    int* deg = (int*)w;                         w += ((size_t)N + 64) * 4;
    int* csr = (int*)w;                         w += (size_t)N * CAP * 4;
    unsigned* bstream = (unsigned*)w;           w += (size_t)NBA * nbkt * SCAP * 4;
    unsigned char* cnts = (unsigned char*)w;    w += ((size_t)NBA * nbkt + 3) & ~3ull;
    unsigned short* entb = (unsigned short*)w;  w += (size_t)N * 64 * 2;
    int* perm = (int*)w;                        w += ((size_t)N + 64) * 4;
    unsigned short* emb1b = (unsigned short*)bstream;  // alias (see above)

    const int n4 = N * 16;                      // float4s to cast
    const int E4 = E / 4;                       // 400000 int4-edges
    const int castB = (n4 + 511) / 512;         // 3125 cast blocks
    const int hb = (N + 31) / 32;

    // k1: buildA counting-sort || Wuv projection || ent->bf16 cast
    buildA_kernel<<<NBA + 16 + castB, 512, 0, stream_>>>(
        head, tail, etype, bstream, cnts, W, rel, Wuvb, ent, entb,
        E4, nbkt, n4, R);

    // k2: pure binB (512 threads per bucket)
    binB_kernel<<<nbkt, 512, 0, stream_>>>(cnts, bstream, deg, csr, perm,
                                           nbkt, N);

    // hop 1
    hop_kernel<<<hb, 512, 0, stream_>>>(deg, csr, perm, Wuvb, entb, ent,
                                        emb1b, out, N);
    // hop 2 (res in place)
    hop_kernel<<<hb, 512, 0, stream_>>>(deg, csr, perm, Wuvb, emb1b, out,
                                        nullptr, out, N);
}